// Round 6
// baseline (377.823 us; speedup 1.0000x reference)
//
#include <hip/hip_runtime.h>
#include <stdint.h>

typedef unsigned short u16;
typedef uint32_t u32;
typedef u16      u16x8 __attribute__((ext_vector_type(8)));
typedef _Float16 f16x8 __attribute__((ext_vector_type(8)));
typedef _Float16 f16x2 __attribute__((ext_vector_type(2)));
typedef float    f32x4 __attribute__((ext_vector_type(4)));
typedef unsigned long long u64;

#define HIDDEN 128   // NH(8) * HD(16)
#define BSH    9     // bucket shift: 512 nodes/bucket
#define NPB    (1 << BSH)
#define MAXBUK 256   // (n+NPB-1)>>BSH = 196 for n=100000
#define NBLK   256   // hist/scatter block count (chunk-partitioned)

// INPUTS fp32, OUTPUT fp32. W/Q/K/V stored fp16 (absmax 0.031 vs 0.105
// threshold), all accumulation fp32.
//
// Round 6: revert round-5 fusion (occupancy collapse 75->54%, total +25us).
// Round-4 structure restored (attn_kernel/csr_finalize verbatim — attn is at
// its ~116us random-gather floor, pinned 3.88 TB/s L2-fill across rounds).
// New this round:
//  - CSR reservation made atomic-free: chunked bucket_hist stores per-block
//    histograms; csr_scan derives per-(block,bucket) bases; bucket_scatter
//    drops its histogram pass (2 passes instead of 3, no global atomics,
//    no memset dispatch).
//  - qkv: 2 row-tiles per wave (block=128 rows) -> each B-fragment load feeds
//    2 MFMAs (halves B-load traffic), identical fragment mappings.

__device__ __forceinline__ float h2f(u16 u) {
    _Float16 h; __builtin_memcpy(&h, &u, 2); return (float)h;
}
__device__ __forceinline__ u16 f2h(float f) {
    _Float16 h = (_Float16)f; u16 u; __builtin_memcpy(&u, &h, 2); return u;
}
__device__ __forceinline__ f16x2 as_h2(uint32_t u) {
    return __builtin_bit_cast(f16x2, u);
}

// quad_perm DPP cross-lane: CTRL=0xB1 -> lane^1, CTRL=0x4E -> lane^2
template <int CTRL>
__device__ __forceinline__ float dpp_qperm(float x) {
#if __has_builtin(__builtin_amdgcn_update_dpp)
    int r = __builtin_amdgcn_update_dpp(0, __builtin_bit_cast(int, x), CTRL, 0xF, 0xF, true);
    return __builtin_bit_cast(float, r);
#else
    return __shfl_xor(x, (CTRL == 0xB1) ? 1 : 2);
#endif
}

__device__ __forceinline__ float fdot2(f16x2 a, f16x2 b, float c) {
#if __has_builtin(__builtin_amdgcn_fdot2)
    return __builtin_amdgcn_fdot2(a, b, c, false);
#else
    return c + (float)a.x * (float)b.x + (float)a.y * (float)b.y;
#endif
}

__device__ __forceinline__ float exp2f_fast(float x) {
#if __has_builtin(__builtin_amdgcn_exp2f)
    return __builtin_amdgcn_exp2f(x);
#else
    return __expf(x * 0.6931471805599453f);
#endif
}

// ---------------------------------------------------------------------------
// Pack [Wq|Wk|Wv] (128x128 row-major fp32 W[k][c]) into fp16 MFMA B-fragment
// order for mfma_f32_16x16x32_f16: lane l elem j holds
// B[k = kt*32 + (l>>4)*8 + j][c = (ct&7)*16 + (l&15)], ct = w*8 + col_tile.
// ---------------------------------------------------------------------------
__global__ void pack_w_kernel(const float* __restrict__ Wq, const float* __restrict__ Wk,
                              const float* __restrict__ Wv, u16* __restrict__ packed) {
    int tid = blockIdx.x * blockDim.x + threadIdx.x;
    if (tid >= 24 * 4 * 64 * 8) return;
    int j    = tid & 7;
    int lane = (tid >> 3) & 63;
    int kt   = (tid >> 9) & 3;
    int ct   = tid >> 11;            // 0..23
    int w    = ct >> 3;
    int k    = kt * 32 + ((lane >> 4) << 3) + j;
    int c    = (ct & 7) * 16 + (lane & 15);
    const float* W = (w == 0) ? Wq : (w == 1) ? Wk : Wv;
    packed[tid] = f2h(W[k * HIDDEN + c]);
}

// ---------------------------------------------------------------------------
// MFMA QKV projection. Block 256 = 4 waves; block covers 128 rows; each wave
// owns two 16-row tiles (rows wave*16.. and +64) so every B-fragment load
// feeds 2 MFMAs. Q row-major fp16; K/V interleaved for attn:
//   u16 index = node*256 + (cc>>2)*8 + (isV ? 4 : 0) + (cc&3)
// ---------------------------------------------------------------------------
__global__ __launch_bounds__(256) void qkv_gemm_mfma(
    const float* __restrict__ h, const u16* __restrict__ packed,
    const float* __restrict__ bq, const float* __restrict__ bk, const float* __restrict__ bv,
    u16* __restrict__ Qb, u16* __restrict__ KVb, int n) {
    int wave = threadIdx.x >> 6, lane = threadIdx.x & 63;
    int m = lane & 15, quad = lane >> 4;
    int row0A = blockIdx.x * 128 + wave * 16;
    int row0B = row0A + 64;
    int arowA = row0A + m;
    int arowB = row0B + m;

    u16x8 a0[4], a1[4];
    if (arowA < n) {
        const float* hp = h + (size_t)arowA * HIDDEN + quad * 8;
        #pragma unroll
        for (int kt = 0; kt < 4; ++kt) {
            f32x4 lo = *(const f32x4*)(hp + kt * 32);
            f32x4 hi = *(const f32x4*)(hp + kt * 32 + 4);
            #pragma unroll
            for (int j = 0; j < 4; ++j) {
                a0[kt][j]     = f2h(lo[j]);
                a0[kt][j + 4] = f2h(hi[j]);
            }
        }
    } else {
        #pragma unroll
        for (int kt = 0; kt < 4; ++kt) a0[kt] = (u16x8){0,0,0,0,0,0,0,0};
    }
    if (arowB < n) {
        const float* hp = h + (size_t)arowB * HIDDEN + quad * 8;
        #pragma unroll
        for (int kt = 0; kt < 4; ++kt) {
            f32x4 lo = *(const f32x4*)(hp + kt * 32);
            f32x4 hi = *(const f32x4*)(hp + kt * 32 + 4);
            #pragma unroll
            for (int j = 0; j < 4; ++j) {
                a1[kt][j]     = f2h(lo[j]);
                a1[kt][j + 4] = f2h(hi[j]);
            }
        }
    } else {
        #pragma unroll
        for (int kt = 0; kt < 4; ++kt) a1[kt] = (u16x8){0,0,0,0,0,0,0,0};
    }

    #pragma unroll
    for (int ct = 0; ct < 24; ++ct) {
        f32x4 acc0 = {0.f, 0.f, 0.f, 0.f};
        f32x4 acc1 = {0.f, 0.f, 0.f, 0.f};
        #pragma unroll
        for (int kt = 0; kt < 4; ++kt) {
            u16x8 b = *(const u16x8*)(packed + (((ct * 4 + kt) * 64 + lane) << 3));
            acc0 = __builtin_amdgcn_mfma_f32_16x16x32_f16(
                __builtin_bit_cast(f16x8, a0[kt]), __builtin_bit_cast(f16x8, b),
                acc0, 0, 0, 0);
            acc1 = __builtin_amdgcn_mfma_f32_16x16x32_f16(
                __builtin_bit_cast(f16x8, a1[kt]), __builtin_bit_cast(f16x8, b),
                acc1, 0, 0, 0);
        }
        int w  = ct >> 3;                 // compile-time after unroll
        int cc = (ct & 7) * 16 + m;
        const float* bp = (w == 0) ? bq : (w == 1) ? bk : bv;
        float bias = bp[cc];
        #pragma unroll
        for (int r = 0; r < 4; ++r) {
            int rrA = row0A + quad * 4 + r;
            int rrB = row0B + quad * 4 + r;
            if (rrA < n) {
                u16 val = f2h(acc0[r] + bias);
                if (w == 0) Qb[(size_t)rrA * HIDDEN + cc] = val;
                else KVb[(size_t)rrA * 256 + ((cc >> 2) << 3) + ((w == 2) ? 4 : 0) + (cc & 3)] = val;
            }
            if (rrB < n) {
                u16 val = f2h(acc1[r] + bias);
                if (w == 0) Qb[(size_t)rrB * HIDDEN + cc] = val;
                else KVb[(size_t)rrB * 256 + ((cc >> 2) << 3) + ((w == 2) ? 4 : 0) + (cc & 3)] = val;
            }
        }
    }
}

// ---------------------------------------------------------------------------
// CSR build, atomic-free reservation.
// Phase 1: chunked histogram; block b stores its 256-bucket histogram.
// ---------------------------------------------------------------------------
__global__ __launch_bounds__(256) void bucket_hist(const int* __restrict__ dst,
                                                   int* __restrict__ histAll,
                                                   int e, int nbuk, int chunk) {
    __shared__ int lh[MAXBUK];
    int t = threadIdx.x;
    lh[t] = 0;
    __syncthreads();
    int lo = blockIdx.x * chunk;
    int hi = lo + chunk; if (hi > e) hi = e;
    for (int i = lo + t; i < hi; i += 256) {
        int b = dst[i] >> BSH;
        if (b < 0) b = 0; if (b >= nbuk) b = nbuk - 1;
        atomicAdd(&lh[b], 1);
    }
    __syncthreads();
    histAll[blockIdx.x * MAXBUK + t] = lh[t];
}

// Phase 2 (1 block, 256 thr; thread t owns bucket t): per-(block,bucket)
// exclusive bases + bucket-total exclusive scan -> bs[].
__global__ __launch_bounds__(256) void csr_scan(const int* __restrict__ histAll,
                                                int* __restrict__ baseAll,
                                                int* __restrict__ bs,
                                                int nbuk, int e, int nblk) {
    __shared__ int buf[256];
    int t = threadIdx.x;
    int run = 0;
    for (int b = 0; b < nblk; ++b) {
        int v = histAll[b * MAXBUK + t];
        baseAll[b * MAXBUK + t] = run;
        run += v;
    }
    buf[t] = run;                        // total count of bucket t
    __syncthreads();
    #pragma unroll
    for (int off = 1; off < 256; off <<= 1) {
        int x = (t >= off) ? buf[t - off] : 0;
        __syncthreads();
        buf[t] += x;
        __syncthreads();
    }
    int excl = buf[t] - run;
    if (t < nbuk) bs[t] = excl;
    if (t == 0) bs[nbuk] = e;
}

// Phase 3: scatter, no histogram pass, no global atomics. Pairs packed u32:
// ((d & 511) << 17) | (src & 0x1FFFF); bucket implied by position.
__global__ __launch_bounds__(256) void bucket_scatter(
    const int* __restrict__ src, const int* __restrict__ dst,
    const int* __restrict__ bs, const int* __restrict__ baseAll,
    u32* __restrict__ pairs, int e, int nbuk, int chunk) {
    __shared__ int lcur[MAXBUK];
    int t = threadIdx.x;
    int lo = blockIdx.x * chunk;
    int hi = lo + chunk; if (hi > e) hi = e;
    if (lo >= e) return;                 // uniform per block
    lcur[t] = ((t < nbuk) ? bs[t] : 0) + baseAll[blockIdx.x * MAXBUK + t];
    __syncthreads();
    for (int i = lo + t; i < hi; i += 256) {
        int d = dst[i], s = src[i];
        int b = d >> BSH;
        if (b < 0) b = 0; if (b >= nbuk) b = nbuk - 1;
        int slot = atomicAdd(&lcur[b], 1);
        if (slot >= 0 && slot < e)
            pairs[slot] = (((u32)d & (NPB - 1)) << 17) | ((u32)s & 0x1FFFF);
    }
}

// Phase 4: per-bucket finalize (verbatim round-4). One block per bucket: LDS
// per-dst histogram, LDS scan, LDS-atomic ranking. Emits compact starts[].
__global__ __launch_bounds__(1024) void csr_finalize(
    const u32* __restrict__ pairs, const int* __restrict__ bs,
    int* __restrict__ starts, int* __restrict__ srcperm, int n, int e, int nbuk) {
    __shared__ int hist[NPB];
    __shared__ int excl[NPB];
    __shared__ int lcur[NPB];
    int b = blockIdx.x;
    int t = threadIdx.x;
    int d0 = b << BSH;
    int lo = bs[b], hi = bs[b + 1];
    for (int i = t; i < NPB; i += 1024) { hist[i] = 0; lcur[i] = 0; }
    __syncthreads();
    for (int i = lo + t; i < hi; i += 1024) {
        int ld = (int)(pairs[i] >> 17);          // 9 bits by construction
        atomicAdd(&hist[ld], 1);
    }
    __syncthreads();
    if (t < NPB) excl[t] = hist[t];
    __syncthreads();
    #pragma unroll
    for (int off = 1; off < NPB; off <<= 1) {
        int x = 0;
        if (t < NPB && t >= off) x = excl[t - off];
        __syncthreads();
        if (t < NPB) excl[t] += x;
        __syncthreads();
    }
    if (t < NPB) excl[t] -= hist[t];     // inclusive -> exclusive
    __syncthreads();
    if (t < NPB) {
        int d = d0 + t;
        if (d < n) starts[d] = lo + excl[t];
    }
    if (b == nbuk - 1 && t == 0) starts[n] = e;
    for (int i = lo + t; i < hi; i += 1024) {
        u32 p = pairs[i];
        int ld = (int)(p >> 17);
        int s  = (int)(p & 0x1FFFF);
        int r = atomicAdd(&lcur[ld], 1);
        int slot = lo + excl[ld] + r;
        if (slot >= 0 && slot < e) srcperm[slot] = s;
    }
}

// ---------------------------------------------------------------------------
// attn (verbatim round-4). One wave per dst node, two 32-lane halves over
// even/odd edges with independent online-softmax states (merged at end).
// ---------------------------------------------------------------------------
__global__ __launch_bounds__(256) void attn_kernel(
    const u16* __restrict__ Qb, const uint4* __restrict__ KVb,
    const int* __restrict__ starts, const int* __restrict__ srcperm,
    float* __restrict__ out, int n, int e) {
    int node = blockIdx.x * 4 + (threadIdx.x >> 6);
    int lane = threadIdx.x & 63;
    if (node >= n) return;
    int j = lane & 31;      // dim group: dims 4j..4j+3
    int h = lane >> 5;      // half: processes edges with (idx & 1) == h

    uint2 qp = *(const uint2*)(Qb + (size_t)node * HIDDEN + j * 4);
    f16x2 q01 = as_h2(qp.x), q23 = as_h2(qp.y);

    int off = starts[node];
    int deg = starts[node + 1] - off;
    if (deg < 0) deg = 0; if (deg > e) deg = e;
    if (off < 0) off = 0; if (off > e - deg) off = e - deg;

    const float LOG2E = 1.44269504f;
    float mrun = -1e30f, lrun = 0.f;
    float o0 = 0.f, o1 = 0.f, o2 = 0.f, o3 = 0.f;

    if (deg > 0) {
        const int last = deg - 1;
        const int* sp = srcperm + off;
        #define IDX(ii) (sp[((ii) > last) ? last : (ii)])
        #define KVL(s)  (KVb[(size_t)(((unsigned)(s) < (unsigned)n) ? (unsigned)(s) : 0u) * 32 + j])

        int sA = IDX(h);
        int sB = IDX(h + 2);
        int sC = IDX(h + 4);
        int sD = IDX(h + 6);
        uint4 kvA = KVL(sA);
        uint4 kvB = KVL(sB);
        (void)sA;

        for (int i = 0; i < deg; i += 2) {
            uint4 kv = kvA;
            kvA = kvB;
            kvB = KVL(sC);                  // prefetch edge i+4+h
            sC = sD;
            sD = IDX(i + 8 + h);            // prefetch index for edge i+8+h

            float p = fdot2(as_h2(kv.x), q01, fdot2(as_h2(kv.y), q23, 0.f));
            p += dpp_qperm<0xB1>(p);        // lane^1
            p += dpp_qperm<0x4E>(p);        // lane^2 -> head sum in all 4
            p *= LOG2E;                     // exp2 domain
            bool valid = (i + h) < deg;
            float pv = valid ? p : -1e30f;
            float mn  = fmaxf(mrun, pv);
            float scl = exp2f_fast(mrun - mn);
            float w   = valid ? exp2f_fast(pv - mn) : 0.f;
            lrun = lrun * scl + w;
            f16x2 vz = as_h2(kv.z), vw = as_h2(kv.w);
            o0 = o0 * scl + w * (float)vz.x;
            o1 = o1 * scl + w * (float)vz.y;
            o2 = o2 * scl + w * (float)vw.x;
            o3 = o3 * scl + w * (float)vw.y;
            mrun = mn;
        }
        #undef IDX
        #undef KVL
    }

    // merge the two half-wave states
    float mo  = __shfl_xor(mrun, 32);
    float lo_ = __shfl_xor(lrun, 32);
    float p0 = __shfl_xor(o0, 32), p1 = __shfl_xor(o1, 32);
    float p2 = __shfl_xor(o2, 32), p3 = __shfl_xor(o3, 32);
    float m2 = fmaxf(mrun, mo);
    float sa = exp2f_fast(mrun - m2), sb = exp2f_fast(mo - m2);
    float l  = lrun * sa + lo_ * sb;
    float inv = (l > 0.f) ? 1.f / l : 0.f;
    if (h == 0) {
        float4 r;
        r.x = (o0 * sa + p0 * sb) * inv;
        r.y = (o1 * sa + p1 * sb) * inv;
        r.z = (o2 * sa + p2 * sb) * inv;
        r.w = (o3 * sa + p3 * sb) * inv;
        *(float4*)(out + (size_t)node * HIDDEN + j * 4) = r;
    }
}

// ---------------------------------------------------------------------------
extern "C" void kernel_launch(void* const* d_in, const int* in_sizes, int n_in,
                              void* d_out, int out_size, void* d_ws, size_t ws_size,
                              hipStream_t stream) {
    const float* h   = (const float*)d_in[0];
    const int*   src = (const int*)d_in[1];
    const int*   dst = (const int*)d_in[2];
    const float* Wq  = (const float*)d_in[3];
    const float* bq  = (const float*)d_in[4];
    const float* Wk  = (const float*)d_in[5];
    const float* bk  = (const float*)d_in[6];
    const float* Wv  = (const float*)d_in[7];
    const float* bv  = (const float*)d_in[8];
    float* out = (float*)d_out;

    const int n = in_sizes[0] / HIDDEN;   // 100000
    const int e = in_sizes[1];            // 1600000
    const int nbuk = (n + NPB - 1) >> BSH; // 196 (<= MAXBUK)

    // Workspace carve — ~84.2 MB (ws_size >= 84.5 MB proven).
    char* ws = (char*)d_ws;
    auto align256 = [](size_t x) { return (x + 255) & ~(size_t)255; };
    int* starts  = (int*)ws; ws += align256((size_t)(n + 1) * 4);
    int* bs      = (int*)ws; ws += align256((size_t)(MAXBUK + 1) * 4);
    int* histAll = (int*)ws; ws += align256((size_t)NBLK * MAXBUK * 4);
    int* baseAll = (int*)ws; ws += align256((size_t)NBLK * MAXBUK * 4);
    int* srcperm = (int*)ws; ws += align256((size_t)e * 4);
    u16* packed  = (u16*)ws; ws += align256((size_t)24 * 4 * 64 * 8 * sizeof(u16));
    u16* Qb      = (u16*)ws; ws += align256((size_t)n * HIDDEN * sizeof(u16));
    u16* KVb     = (u16*)ws; ws += align256((size_t)n * 256 * sizeof(u16));

    // pairs scratch in d_out (e*4 = 6.4MB <= 51.2MB); consumed by
    // csr_finalize before attn writes out.
    u32* pairs = (u32*)d_out;

    const int chunk = (e + NBLK - 1) / NBLK;

    pack_w_kernel<<<(24 * 4 * 64 * 8 + 255) / 256, 256, 0, stream>>>(Wq, Wk, Wv, packed);
    qkv_gemm_mfma<<<(n + 127) / 128, 256, 0, stream>>>(h, packed, bq, bk, bv, Qb, KVb, n);

    bucket_hist<<<NBLK, 256, 0, stream>>>(dst, histAll, e, nbuk, chunk);
    csr_scan<<<1, 256, 0, stream>>>(histAll, baseAll, bs, nbuk, e, NBLK);
    bucket_scatter<<<NBLK, 256, 0, stream>>>(src, dst, bs, baseAll, pairs, e, nbuk, chunk);
    csr_finalize<<<nbuk, 1024, 0, stream>>>(pairs, bs, starts, srcperm, n, e, nbuk);

    attn_kernel<<<(n + 3) / 4, 256, 0, stream>>>(Qb, (const uint4*)KVb, starts, srcperm,
                                                 out, n, e);
}

// Round 7
// 323.536 us; speedup vs baseline: 1.1678x; 1.1678x over previous
//
#include <hip/hip_runtime.h>
#include <stdint.h>

typedef unsigned short u16;
typedef uint32_t u32;
typedef u16      u16x8 __attribute__((ext_vector_type(8)));
typedef _Float16 f16x8 __attribute__((ext_vector_type(8)));
typedef _Float16 f16x2 __attribute__((ext_vector_type(2)));
typedef float    f32x4 __attribute__((ext_vector_type(4)));
typedef unsigned long long u64;

#define HIDDEN 128   // NH(8) * HD(16)
#define BSH    9     // bucket shift: 512 nodes/bucket
#define NPB    (1 << BSH)
#define MAXBUK 256   // (n+NPB-1)>>BSH = 196 for n=100000
#define NBLK   256   // hist/scatter block count (chunk-partitioned)

// INPUTS fp32, OUTPUT fp32. W/Q/K/V stored fp16 (absmax 0.031 vs 0.105
// threshold), all accumulation fp32.
//
// Round 7: round-6 regression localized to csr_scan (single block, 256
// SERIAL strided-row iterations over histAll -> one CU busy ~30-90us while
// 255 idle; attn invariant at 116us proves the rest was clean). Fix:
// parallel column scan.
//  - csr_colscan: 256 blocks (one per bucket); LDS Hillis-Steele over the
//    bucket's per-chunk counts -> baseAll + totals.  (~3us)
//  - bs_scan: 1-block 256-wide exclusive scan of totals -> bs.  (~2us)
// Everything else verbatim round 6 (attn/finalize/scatter/hist/qkv-2row).

__device__ __forceinline__ float h2f(u16 u) {
    _Float16 h; __builtin_memcpy(&h, &u, 2); return (float)h;
}
__device__ __forceinline__ u16 f2h(float f) {
    _Float16 h = (_Float16)f; u16 u; __builtin_memcpy(&u, &h, 2); return u;
}
__device__ __forceinline__ f16x2 as_h2(uint32_t u) {
    return __builtin_bit_cast(f16x2, u);
}

// quad_perm DPP cross-lane: CTRL=0xB1 -> lane^1, CTRL=0x4E -> lane^2
template <int CTRL>
__device__ __forceinline__ float dpp_qperm(float x) {
#if __has_builtin(__builtin_amdgcn_update_dpp)
    int r = __builtin_amdgcn_update_dpp(0, __builtin_bit_cast(int, x), CTRL, 0xF, 0xF, true);
    return __builtin_bit_cast(float, r);
#else
    return __shfl_xor(x, (CTRL == 0xB1) ? 1 : 2);
#endif
}

__device__ __forceinline__ float fdot2(f16x2 a, f16x2 b, float c) {
#if __has_builtin(__builtin_amdgcn_fdot2)
    return __builtin_amdgcn_fdot2(a, b, c, false);
#else
    return c + (float)a.x * (float)b.x + (float)a.y * (float)b.y;
#endif
}

__device__ __forceinline__ float exp2f_fast(float x) {
#if __has_builtin(__builtin_amdgcn_exp2f)
    return __builtin_amdgcn_exp2f(x);
#else
    return __expf(x * 0.6931471805599453f);
#endif
}

// ---------------------------------------------------------------------------
// Pack [Wq|Wk|Wv] (128x128 row-major fp32 W[k][c]) into fp16 MFMA B-fragment
// order for mfma_f32_16x16x32_f16: lane l elem j holds
// B[k = kt*32 + (l>>4)*8 + j][c = (ct&7)*16 + (l&15)], ct = w*8 + col_tile.
// ---------------------------------------------------------------------------
__global__ void pack_w_kernel(const float* __restrict__ Wq, const float* __restrict__ Wk,
                              const float* __restrict__ Wv, u16* __restrict__ packed) {
    int tid = blockIdx.x * blockDim.x + threadIdx.x;
    if (tid >= 24 * 4 * 64 * 8) return;
    int j    = tid & 7;
    int lane = (tid >> 3) & 63;
    int kt   = (tid >> 9) & 3;
    int ct   = tid >> 11;            // 0..23
    int w    = ct >> 3;
    int k    = kt * 32 + ((lane >> 4) << 3) + j;
    int c    = (ct & 7) * 16 + (lane & 15);
    const float* W = (w == 0) ? Wq : (w == 1) ? Wk : Wv;
    packed[tid] = f2h(W[k * HIDDEN + c]);
}

// ---------------------------------------------------------------------------
// MFMA QKV projection. Block 256 = 4 waves; block covers 128 rows; each wave
// owns two 16-row tiles (rows wave*16.. and +64) so every B-fragment load
// feeds 2 MFMAs. Q row-major fp16; K/V interleaved for attn:
//   u16 index = node*256 + (cc>>2)*8 + (isV ? 4 : 0) + (cc&3)
// ---------------------------------------------------------------------------
__global__ __launch_bounds__(256) void qkv_gemm_mfma(
    const float* __restrict__ h, const u16* __restrict__ packed,
    const float* __restrict__ bq, const float* __restrict__ bk, const float* __restrict__ bv,
    u16* __restrict__ Qb, u16* __restrict__ KVb, int n) {
    int wave = threadIdx.x >> 6, lane = threadIdx.x & 63;
    int m = lane & 15, quad = lane >> 4;
    int row0A = blockIdx.x * 128 + wave * 16;
    int row0B = row0A + 64;
    int arowA = row0A + m;
    int arowB = row0B + m;

    u16x8 a0[4], a1[4];
    if (arowA < n) {
        const float* hp = h + (size_t)arowA * HIDDEN + quad * 8;
        #pragma unroll
        for (int kt = 0; kt < 4; ++kt) {
            f32x4 lo = *(const f32x4*)(hp + kt * 32);
            f32x4 hi = *(const f32x4*)(hp + kt * 32 + 4);
            #pragma unroll
            for (int j = 0; j < 4; ++j) {
                a0[kt][j]     = f2h(lo[j]);
                a0[kt][j + 4] = f2h(hi[j]);
            }
        }
    } else {
        #pragma unroll
        for (int kt = 0; kt < 4; ++kt) a0[kt] = (u16x8){0,0,0,0,0,0,0,0};
    }
    if (arowB < n) {
        const float* hp = h + (size_t)arowB * HIDDEN + quad * 8;
        #pragma unroll
        for (int kt = 0; kt < 4; ++kt) {
            f32x4 lo = *(const f32x4*)(hp + kt * 32);
            f32x4 hi = *(const f32x4*)(hp + kt * 32 + 4);
            #pragma unroll
            for (int j = 0; j < 4; ++j) {
                a1[kt][j]     = f2h(lo[j]);
                a1[kt][j + 4] = f2h(hi[j]);
            }
        }
    } else {
        #pragma unroll
        for (int kt = 0; kt < 4; ++kt) a1[kt] = (u16x8){0,0,0,0,0,0,0,0};
    }

    #pragma unroll
    for (int ct = 0; ct < 24; ++ct) {
        f32x4 acc0 = {0.f, 0.f, 0.f, 0.f};
        f32x4 acc1 = {0.f, 0.f, 0.f, 0.f};
        #pragma unroll
        for (int kt = 0; kt < 4; ++kt) {
            u16x8 b = *(const u16x8*)(packed + (((ct * 4 + kt) * 64 + lane) << 3));
            acc0 = __builtin_amdgcn_mfma_f32_16x16x32_f16(
                __builtin_bit_cast(f16x8, a0[kt]), __builtin_bit_cast(f16x8, b),
                acc0, 0, 0, 0);
            acc1 = __builtin_amdgcn_mfma_f32_16x16x32_f16(
                __builtin_bit_cast(f16x8, a1[kt]), __builtin_bit_cast(f16x8, b),
                acc1, 0, 0, 0);
        }
        int w  = ct >> 3;                 // compile-time after unroll
        int cc = (ct & 7) * 16 + m;
        const float* bp = (w == 0) ? bq : (w == 1) ? bk : bv;
        float bias = bp[cc];
        #pragma unroll
        for (int r = 0; r < 4; ++r) {
            int rrA = row0A + quad * 4 + r;
            int rrB = row0B + quad * 4 + r;
            if (rrA < n) {
                u16 val = f2h(acc0[r] + bias);
                if (w == 0) Qb[(size_t)rrA * HIDDEN + cc] = val;
                else KVb[(size_t)rrA * 256 + ((cc >> 2) << 3) + ((w == 2) ? 4 : 0) + (cc & 3)] = val;
            }
            if (rrB < n) {
                u16 val = f2h(acc1[r] + bias);
                if (w == 0) Qb[(size_t)rrB * HIDDEN + cc] = val;
                else KVb[(size_t)rrB * 256 + ((cc >> 2) << 3) + ((w == 2) ? 4 : 0) + (cc & 3)] = val;
            }
        }
    }
}

// ---------------------------------------------------------------------------
// CSR build, atomic-free reservation.
// Phase 1: chunked histogram; block b stores its 256-bucket histogram.
// ---------------------------------------------------------------------------
__global__ __launch_bounds__(256) void bucket_hist(const int* __restrict__ dst,
                                                   int* __restrict__ histAll,
                                                   int e, int nbuk, int chunk) {
    __shared__ int lh[MAXBUK];
    int t = threadIdx.x;
    lh[t] = 0;
    __syncthreads();
    int lo = blockIdx.x * chunk;
    int hi = lo + chunk; if (hi > e) hi = e;
    for (int i = lo + t; i < hi; i += 256) {
        int b = dst[i] >> BSH;
        if (b < 0) b = 0; if (b >= nbuk) b = nbuk - 1;
        atomicAdd(&lh[b], 1);
    }
    __syncthreads();
    histAll[blockIdx.x * MAXBUK + t] = lh[t];
}

// Phase 2a: parallel column scan. One block per bucket b: Hillis-Steele over
// histAll[i][b] (i = chunk block) -> baseAll[i][b]; bucket total -> totals[b].
__global__ __launch_bounds__(256) void csr_colscan(const int* __restrict__ histAll,
                                                   int* __restrict__ baseAll,
                                                   int* __restrict__ totals,
                                                   int nblk) {
    __shared__ int buf[256];
    int b = blockIdx.x;
    int t = threadIdx.x;
    int v = (t < nblk) ? histAll[t * MAXBUK + b] : 0;
    buf[t] = v;
    __syncthreads();
    #pragma unroll
    for (int off = 1; off < 256; off <<= 1) {
        int x = (t >= off) ? buf[t - off] : 0;
        __syncthreads();
        buf[t] += x;
        __syncthreads();
    }
    if (t < nblk) baseAll[t * MAXBUK + b] = buf[t] - v;   // exclusive within bucket
    if (t == 255) totals[b] = buf[255];
}

// Phase 2b: exclusive scan of bucket totals -> bs[].
__global__ __launch_bounds__(256) void bs_scan(const int* __restrict__ totals,
                                               int* __restrict__ bs, int nbuk, int e) {
    __shared__ int buf[256];
    int t = threadIdx.x;
    int v = totals[t];
    buf[t] = v;
    __syncthreads();
    #pragma unroll
    for (int off = 1; off < 256; off <<= 1) {
        int x = (t >= off) ? buf[t - off] : 0;
        __syncthreads();
        buf[t] += x;
        __syncthreads();
    }
    if (t < nbuk) bs[t] = buf[t] - v;
    if (t == 0) bs[nbuk] = e;
}

// Phase 3: scatter, no histogram pass, no global atomics. Pairs packed u32:
// ((d & 511) << 17) | (src & 0x1FFFF); bucket implied by position.
__global__ __launch_bounds__(256) void bucket_scatter(
    const int* __restrict__ src, const int* __restrict__ dst,
    const int* __restrict__ bs, const int* __restrict__ baseAll,
    u32* __restrict__ pairs, int e, int nbuk, int chunk) {
    __shared__ int lcur[MAXBUK];
    int t = threadIdx.x;
    int lo = blockIdx.x * chunk;
    int hi = lo + chunk; if (hi > e) hi = e;
    if (lo >= e) return;                 // uniform per block
    lcur[t] = ((t < nbuk) ? bs[t] : 0) + baseAll[blockIdx.x * MAXBUK + t];
    __syncthreads();
    for (int i = lo + t; i < hi; i += 256) {
        int d = dst[i], s = src[i];
        int b = d >> BSH;
        if (b < 0) b = 0; if (b >= nbuk) b = nbuk - 1;
        int slot = atomicAdd(&lcur[b], 1);
        if (slot >= 0 && slot < e)
            pairs[slot] = (((u32)d & (NPB - 1)) << 17) | ((u32)s & 0x1FFFF);
    }
}

// Phase 4: per-bucket finalize (verbatim). One block per bucket: LDS per-dst
// histogram, LDS scan, LDS-atomic ranking. Emits compact starts[].
__global__ __launch_bounds__(1024) void csr_finalize(
    const u32* __restrict__ pairs, const int* __restrict__ bs,
    int* __restrict__ starts, int* __restrict__ srcperm, int n, int e, int nbuk) {
    __shared__ int hist[NPB];
    __shared__ int excl[NPB];
    __shared__ int lcur[NPB];
    int b = blockIdx.x;
    int t = threadIdx.x;
    int d0 = b << BSH;
    int lo = bs[b], hi = bs[b + 1];
    for (int i = t; i < NPB; i += 1024) { hist[i] = 0; lcur[i] = 0; }
    __syncthreads();
    for (int i = lo + t; i < hi; i += 1024) {
        int ld = (int)(pairs[i] >> 17);          // 9 bits by construction
        atomicAdd(&hist[ld], 1);
    }
    __syncthreads();
    if (t < NPB) excl[t] = hist[t];
    __syncthreads();
    #pragma unroll
    for (int off = 1; off < NPB; off <<= 1) {
        int x = 0;
        if (t < NPB && t >= off) x = excl[t - off];
        __syncthreads();
        if (t < NPB) excl[t] += x;
        __syncthreads();
    }
    if (t < NPB) excl[t] -= hist[t];     // inclusive -> exclusive
    __syncthreads();
    if (t < NPB) {
        int d = d0 + t;
        if (d < n) starts[d] = lo + excl[t];
    }
    if (b == nbuk - 1 && t == 0) starts[n] = e;
    for (int i = lo + t; i < hi; i += 1024) {
        u32 p = pairs[i];
        int ld = (int)(p >> 17);
        int s  = (int)(p & 0x1FFFF);
        int r = atomicAdd(&lcur[ld], 1);
        int slot = lo + excl[ld] + r;
        if (slot >= 0 && slot < e) srcperm[slot] = s;
    }
}

// ---------------------------------------------------------------------------
// attn (verbatim round-4). One wave per dst node, two 32-lane halves over
// even/odd edges with independent online-softmax states (merged at end).
// ---------------------------------------------------------------------------
__global__ __launch_bounds__(256) void attn_kernel(
    const u16* __restrict__ Qb, const uint4* __restrict__ KVb,
    const int* __restrict__ starts, const int* __restrict__ srcperm,
    float* __restrict__ out, int n, int e) {
    int node = blockIdx.x * 4 + (threadIdx.x >> 6);
    int lane = threadIdx.x & 63;
    if (node >= n) return;
    int j = lane & 31;      // dim group: dims 4j..4j+3
    int h = lane >> 5;      // half: processes edges with (idx & 1) == h

    uint2 qp = *(const uint2*)(Qb + (size_t)node * HIDDEN + j * 4);
    f16x2 q01 = as_h2(qp.x), q23 = as_h2(qp.y);

    int off = starts[node];
    int deg = starts[node + 1] - off;
    if (deg < 0) deg = 0; if (deg > e) deg = e;
    if (off < 0) off = 0; if (off > e - deg) off = e - deg;

    const float LOG2E = 1.44269504f;
    float mrun = -1e30f, lrun = 0.f;
    float o0 = 0.f, o1 = 0.f, o2 = 0.f, o3 = 0.f;

    if (deg > 0) {
        const int last = deg - 1;
        const int* sp = srcperm + off;
        #define IDX(ii) (sp[((ii) > last) ? last : (ii)])
        #define KVL(s)  (KVb[(size_t)(((unsigned)(s) < (unsigned)n) ? (unsigned)(s) : 0u) * 32 + j])

        int sA = IDX(h);
        int sB = IDX(h + 2);
        int sC = IDX(h + 4);
        int sD = IDX(h + 6);
        uint4 kvA = KVL(sA);
        uint4 kvB = KVL(sB);
        (void)sA;

        for (int i = 0; i < deg; i += 2) {
            uint4 kv = kvA;
            kvA = kvB;
            kvB = KVL(sC);                  // prefetch edge i+4+h
            sC = sD;
            sD = IDX(i + 8 + h);            // prefetch index for edge i+8+h

            float p = fdot2(as_h2(kv.x), q01, fdot2(as_h2(kv.y), q23, 0.f));
            p += dpp_qperm<0xB1>(p);        // lane^1
            p += dpp_qperm<0x4E>(p);        // lane^2 -> head sum in all 4
            p *= LOG2E;                     // exp2 domain
            bool valid = (i + h) < deg;
            float pv = valid ? p : -1e30f;
            float mn  = fmaxf(mrun, pv);
            float scl = exp2f_fast(mrun - mn);
            float w   = valid ? exp2f_fast(pv - mn) : 0.f;
            lrun = lrun * scl + w;
            f16x2 vz = as_h2(kv.z), vw = as_h2(kv.w);
            o0 = o0 * scl + w * (float)vz.x;
            o1 = o1 * scl + w * (float)vz.y;
            o2 = o2 * scl + w * (float)vw.x;
            o3 = o3 * scl + w * (float)vw.y;
            mrun = mn;
        }
        #undef IDX
        #undef KVL
    }

    // merge the two half-wave states
    float mo  = __shfl_xor(mrun, 32);
    float lo_ = __shfl_xor(lrun, 32);
    float p0 = __shfl_xor(o0, 32), p1 = __shfl_xor(o1, 32);
    float p2 = __shfl_xor(o2, 32), p3 = __shfl_xor(o3, 32);
    float m2 = fmaxf(mrun, mo);
    float sa = exp2f_fast(mrun - m2), sb = exp2f_fast(mo - m2);
    float l  = lrun * sa + lo_ * sb;
    float inv = (l > 0.f) ? 1.f / l : 0.f;
    if (h == 0) {
        float4 r;
        r.x = (o0 * sa + p0 * sb) * inv;
        r.y = (o1 * sa + p1 * sb) * inv;
        r.z = (o2 * sa + p2 * sb) * inv;
        r.w = (o3 * sa + p3 * sb) * inv;
        *(float4*)(out + (size_t)node * HIDDEN + j * 4) = r;
    }
}

// ---------------------------------------------------------------------------
extern "C" void kernel_launch(void* const* d_in, const int* in_sizes, int n_in,
                              void* d_out, int out_size, void* d_ws, size_t ws_size,
                              hipStream_t stream) {
    const float* h   = (const float*)d_in[0];
    const int*   src = (const int*)d_in[1];
    const int*   dst = (const int*)d_in[2];
    const float* Wq  = (const float*)d_in[3];
    const float* bq  = (const float*)d_in[4];
    const float* Wk  = (const float*)d_in[5];
    const float* bk  = (const float*)d_in[6];
    const float* Wv  = (const float*)d_in[7];
    const float* bv  = (const float*)d_in[8];
    float* out = (float*)d_out;

    const int n = in_sizes[0] / HIDDEN;   // 100000
    const int e = in_sizes[1];            // 1600000
    const int nbuk = (n + NPB - 1) >> BSH; // 196 (<= MAXBUK)

    // Workspace carve — ~84.2 MB (ws_size >= 84.5 MB proven).
    char* ws = (char*)d_ws;
    auto align256 = [](size_t x) { return (x + 255) & ~(size_t)255; };
    int* starts  = (int*)ws; ws += align256((size_t)(n + 1) * 4);
    int* bs      = (int*)ws; ws += align256((size_t)(MAXBUK + 1) * 4);
    int* totals  = (int*)ws; ws += align256((size_t)MAXBUK * 4);
    int* histAll = (int*)ws; ws += align256((size_t)NBLK * MAXBUK * 4);
    int* baseAll = (int*)ws; ws += align256((size_t)NBLK * MAXBUK * 4);
    int* srcperm = (int*)ws; ws += align256((size_t)e * 4);
    u16* packed  = (u16*)ws; ws += align256((size_t)24 * 4 * 64 * 8 * sizeof(u16));
    u16* Qb      = (u16*)ws; ws += align256((size_t)n * HIDDEN * sizeof(u16));
    u16* KVb     = (u16*)ws; ws += align256((size_t)n * 256 * sizeof(u16));

    // pairs scratch in d_out (e*4 = 6.4MB <= 51.2MB); consumed by
    // csr_finalize before attn writes out.
    u32* pairs = (u32*)d_out;

    const int chunk = (e + NBLK - 1) / NBLK;

    pack_w_kernel<<<(24 * 4 * 64 * 8 + 255) / 256, 256, 0, stream>>>(Wq, Wk, Wv, packed);
    qkv_gemm_mfma<<<(n + 127) / 128, 256, 0, stream>>>(h, packed, bq, bk, bv, Qb, KVb, n);

    bucket_hist<<<NBLK, 256, 0, stream>>>(dst, histAll, e, nbuk, chunk);
    csr_colscan<<<MAXBUK, 256, 0, stream>>>(histAll, baseAll, totals, NBLK);
    bs_scan<<<1, 256, 0, stream>>>(totals, bs, nbuk, e);
    bucket_scatter<<<NBLK, 256, 0, stream>>>(src, dst, bs, baseAll, pairs, e, nbuk, chunk);
    csr_finalize<<<nbuk, 1024, 0, stream>>>(pairs, bs, starts, srcperm, n, e, nbuk);

    attn_kernel<<<(n + 3) / 4, 256, 0, stream>>>(Qb, (const uint4*)KVb, starts, srcperm,
                                                 out, n, e);
}

// Round 9
// 320.299 us; speedup vs baseline: 1.1796x; 1.0101x over previous
//
#include <hip/hip_runtime.h>
#include <stdint.h>

typedef unsigned short u16;
typedef uint32_t u32;
typedef u16      u16x8 __attribute__((ext_vector_type(8)));
typedef _Float16 f16x8 __attribute__((ext_vector_type(8)));
typedef _Float16 f16x2 __attribute__((ext_vector_type(2)));
typedef __fp16   fp16x2 __attribute__((ext_vector_type(2)));   // builtin return type
typedef float    f32x4 __attribute__((ext_vector_type(4)));
typedef unsigned long long u64;

#define HIDDEN 128   // NH(8) * HD(16)
#define BSH    9     // bucket shift: 512 nodes/bucket
#define NPB    (1 << BSH)
#define MAXBUK 256   // (n+NPB-1)>>BSH = 196 for n=100000
#define NBLK   256   // hist/scatter block count (chunk-partitioned)

// INPUTS fp32, OUTPUT fp32. W/Q/K/V stored fp16 (absmax 0.031 vs 0.105
// threshold), all accumulation fp32.
//
// Round 9 = round 8 with the cvt_pkrtz return-type compile fix (__fp16
// vector, bit_cast to u32). Theory unchanged: qkv epilogue was the hidden
// ~110us hog (192 x 2B scalar stores/thread). SWAPPED MFMA operands
// (W_frag, h_frag) transpose the output fragment so each lane holds 4
// consecutive output cols of one row -> 48 x 8B uint2 stores/thread with
// v_cvt_pkrtz packing. pack_w and loads unchanged (fragment layouts are
// operand-symmetric). Everything else verbatim round 7.

__device__ __forceinline__ float h2f(u16 u) {
    _Float16 h; __builtin_memcpy(&h, &u, 2); return (float)h;
}
__device__ __forceinline__ u16 f2h(float f) {
    _Float16 h = (_Float16)f; u16 u; __builtin_memcpy(&u, &h, 2); return u;
}
__device__ __forceinline__ f16x2 as_h2(uint32_t u) {
    return __builtin_bit_cast(f16x2, u);
}
// pack two f32 -> 2xf16 in one u32 (v_cvt_pkrtz_f16_f32, 1 instr)
__device__ __forceinline__ u32 pk2(float a, float b) {
#if __has_builtin(__builtin_amdgcn_cvt_pkrtz)
    fp16x2 r = __builtin_amdgcn_cvt_pkrtz(a, b);
    return __builtin_bit_cast(u32, r);
#else
    return (u32)f2h(a) | ((u32)f2h(b) << 16);
#endif
}

// quad_perm DPP cross-lane: CTRL=0xB1 -> lane^1, CTRL=0x4E -> lane^2
template <int CTRL>
__device__ __forceinline__ float dpp_qperm(float x) {
#if __has_builtin(__builtin_amdgcn_update_dpp)
    int r = __builtin_amdgcn_update_dpp(0, __builtin_bit_cast(int, x), CTRL, 0xF, 0xF, true);
    return __builtin_bit_cast(float, r);
#else
    return __shfl_xor(x, (CTRL == 0xB1) ? 1 : 2);
#endif
}

__device__ __forceinline__ float fdot2(f16x2 a, f16x2 b, float c) {
#if __has_builtin(__builtin_amdgcn_fdot2)
    return __builtin_amdgcn_fdot2(a, b, c, false);
#else
    return c + (float)a.x * (float)b.x + (float)a.y * (float)b.y;
#endif
}

__device__ __forceinline__ float exp2f_fast(float x) {
#if __has_builtin(__builtin_amdgcn_exp2f)
    return __builtin_amdgcn_exp2f(x);
#else
    return __expf(x * 0.6931471805599453f);
#endif
}

// ---------------------------------------------------------------------------
// Pack [Wq|Wk|Wv] (128x128 row-major fp32 W[k][c]) into fp16 MFMA fragment
// order: lane l elem j holds W[k = kt*32 + (l>>4)*8 + j][c = (ct&7)*16 +
// (l&15)], ct = w*8 + col_tile. (Used as the A-operand = W^T tile.)
// ---------------------------------------------------------------------------
__global__ void pack_w_kernel(const float* __restrict__ Wq, const float* __restrict__ Wk,
                              const float* __restrict__ Wv, u16* __restrict__ packed) {
    int tid = blockIdx.x * blockDim.x + threadIdx.x;
    if (tid >= 24 * 4 * 64 * 8) return;
    int j    = tid & 7;
    int lane = (tid >> 3) & 63;
    int kt   = (tid >> 9) & 3;
    int ct   = tid >> 11;            // 0..23
    int w    = ct >> 3;
    int k    = kt * 32 + ((lane >> 4) << 3) + j;
    int c    = (ct & 7) * 16 + (lane & 15);
    const float* W = (w == 0) ? Wq : (w == 1) ? Wk : Wv;
    packed[tid] = f2h(W[k * HIDDEN + c]);
}

// ---------------------------------------------------------------------------
// MFMA QKV projection, transposed-output form. Block 256 = 4 waves covering
// 128 rows; wave owns rows [wave*16, +16) and [+64, +80). mfma(W_frag,
// h_frag) -> lane holds out[row0 + (lane&15)][(ct&7)*16 + quad*4 + r],
// r=0..3: 4 consecutive cols -> one 8B uint2 store per (ct, tile).
// Q row-major fp16; K/V interleaved for attn:
//   u16 index = node*256 + (cc>>2)*8 + (isV ? 4 : 0) + (cc&3)
// K/V 4-col groups are contiguous in this layout too (8B aligned).
// ---------------------------------------------------------------------------
__global__ __launch_bounds__(256) void qkv_gemm_mfma(
    const float* __restrict__ h, const u16* __restrict__ packed,
    const float* __restrict__ bq, const float* __restrict__ bk, const float* __restrict__ bv,
    u16* __restrict__ Qb, u16* __restrict__ KVb, int n) {
    int wave = threadIdx.x >> 6, lane = threadIdx.x & 63;
    int m = lane & 15, quad = lane >> 4;
    int row0A = blockIdx.x * 128 + wave * 16;
    int row0B = row0A + 64;
    int arowA = row0A + m;
    int arowB = row0B + m;

    u16x8 a0[4], a1[4];
    if (arowA < n) {
        const float* hp = h + (size_t)arowA * HIDDEN + quad * 8;
        #pragma unroll
        for (int kt = 0; kt < 4; ++kt) {
            f32x4 lo = *(const f32x4*)(hp + kt * 32);
            f32x4 hi = *(const f32x4*)(hp + kt * 32 + 4);
            #pragma unroll
            for (int j = 0; j < 4; ++j) {
                a0[kt][j]     = f2h(lo[j]);
                a0[kt][j + 4] = f2h(hi[j]);
            }
        }
    } else {
        #pragma unroll
        for (int kt = 0; kt < 4; ++kt) a0[kt] = (u16x8){0,0,0,0,0,0,0,0};
    }
    if (arowB < n) {
        const float* hp = h + (size_t)arowB * HIDDEN + quad * 8;
        #pragma unroll
        for (int kt = 0; kt < 4; ++kt) {
            f32x4 lo = *(const f32x4*)(hp + kt * 32);
            f32x4 hi = *(const f32x4*)(hp + kt * 32 + 4);
            #pragma unroll
            for (int j = 0; j < 4; ++j) {
                a1[kt][j]     = f2h(lo[j]);
                a1[kt][j + 4] = f2h(hi[j]);
            }
        }
    } else {
        #pragma unroll
        for (int kt = 0; kt < 4; ++kt) a1[kt] = (u16x8){0,0,0,0,0,0,0,0};
    }

    #pragma unroll
    for (int ct = 0; ct < 24; ++ct) {
        f32x4 acc0 = {0.f, 0.f, 0.f, 0.f};
        f32x4 acc1 = {0.f, 0.f, 0.f, 0.f};
        #pragma unroll
        for (int kt = 0; kt < 4; ++kt) {
            u16x8 b = *(const u16x8*)(packed + (((ct * 4 + kt) * 64 + lane) << 3));
            // swapped operands: A = W^T fragment, B = h fragment
            acc0 = __builtin_amdgcn_mfma_f32_16x16x32_f16(
                __builtin_bit_cast(f16x8, b), __builtin_bit_cast(f16x8, a0[kt]),
                acc0, 0, 0, 0);
            acc1 = __builtin_amdgcn_mfma_f32_16x16x32_f16(
                __builtin_bit_cast(f16x8, b), __builtin_bit_cast(f16x8, a1[kt]),
                acc1, 0, 0, 0);
        }
        int w     = ct >> 3;                      // compile-time after unroll
        int cbase = (ct & 7) * 16 + quad * 4;     // 4 consecutive output cols
        const float* bp = (w == 0) ? bq : (w == 1) ? bk : bv;
        float4 bias = *(const float4*)(bp + cbase);

        uint2 pkA, pkB;
        pkA.x = pk2(acc0[0] + bias.x, acc0[1] + bias.y);
        pkA.y = pk2(acc0[2] + bias.z, acc0[3] + bias.w);
        pkB.x = pk2(acc1[0] + bias.x, acc1[1] + bias.y);
        pkB.y = pk2(acc1[2] + bias.z, acc1[3] + bias.w);

        if (w == 0) {
            if (arowA < n) *(uint2*)(Qb + (size_t)arowA * HIDDEN + cbase) = pkA;
            if (arowB < n) *(uint2*)(Qb + (size_t)arowB * HIDDEN + cbase) = pkB;
        } else {
            // KV interleave: 4 consecutive cols share one 8-u16 group slot
            int goff = ((cbase >> 2) << 3) + ((w == 2) ? 4 : 0);
            if (arowA < n) *(uint2*)(KVb + (size_t)arowA * 256 + goff) = pkA;
            if (arowB < n) *(uint2*)(KVb + (size_t)arowB * 256 + goff) = pkB;
        }
    }
}

// ---------------------------------------------------------------------------
// CSR build, atomic-free reservation.
// Phase 1: chunked histogram; block b stores its 256-bucket histogram.
// ---------------------------------------------------------------------------
__global__ __launch_bounds__(256) void bucket_hist(const int* __restrict__ dst,
                                                   int* __restrict__ histAll,
                                                   int e, int nbuk, int chunk) {
    __shared__ int lh[MAXBUK];
    int t = threadIdx.x;
    lh[t] = 0;
    __syncthreads();
    int lo = blockIdx.x * chunk;
    int hi = lo + chunk; if (hi > e) hi = e;
    for (int i = lo + t; i < hi; i += 256) {
        int b = dst[i] >> BSH;
        if (b < 0) b = 0; if (b >= nbuk) b = nbuk - 1;
        atomicAdd(&lh[b], 1);
    }
    __syncthreads();
    histAll[blockIdx.x * MAXBUK + t] = lh[t];
}

// Phase 2a: parallel column scan. One block per bucket b: Hillis-Steele over
// histAll[i][b] (i = chunk block) -> baseAll[i][b]; bucket total -> totals[b].
__global__ __launch_bounds__(256) void csr_colscan(const int* __restrict__ histAll,
                                                   int* __restrict__ baseAll,
                                                   int* __restrict__ totals,
                                                   int nblk) {
    __shared__ int buf[256];
    int b = blockIdx.x;
    int t = threadIdx.x;
    int v = (t < nblk) ? histAll[t * MAXBUK + b] : 0;
    buf[t] = v;
    __syncthreads();
    #pragma unroll
    for (int off = 1; off < 256; off <<= 1) {
        int x = (t >= off) ? buf[t - off] : 0;
        __syncthreads();
        buf[t] += x;
        __syncthreads();
    }
    if (t < nblk) baseAll[t * MAXBUK + b] = buf[t] - v;   // exclusive within bucket
    if (t == 255) totals[b] = buf[255];
}

// Phase 2b: exclusive scan of bucket totals -> bs[].
__global__ __launch_bounds__(256) void bs_scan(const int* __restrict__ totals,
                                               int* __restrict__ bs, int nbuk, int e) {
    __shared__ int buf[256];
    int t = threadIdx.x;
    int v = totals[t];
    buf[t] = v;
    __syncthreads();
    #pragma unroll
    for (int off = 1; off < 256; off <<= 1) {
        int x = (t >= off) ? buf[t - off] : 0;
        __syncthreads();
        buf[t] += x;
        __syncthreads();
    }
    if (t < nbuk) bs[t] = buf[t] - v;
    if (t == 0) bs[nbuk] = e;
}

// Phase 3: scatter, no histogram pass, no global atomics. Pairs packed u32:
// ((d & 511) << 17) | (src & 0x1FFFF); bucket implied by position.
__global__ __launch_bounds__(256) void bucket_scatter(
    const int* __restrict__ src, const int* __restrict__ dst,
    const int* __restrict__ bs, const int* __restrict__ baseAll,
    u32* __restrict__ pairs, int e, int nbuk, int chunk) {
    __shared__ int lcur[MAXBUK];
    int t = threadIdx.x;
    int lo = blockIdx.x * chunk;
    int hi = lo + chunk; if (hi > e) hi = e;
    if (lo >= e) return;                 // uniform per block
    lcur[t] = ((t < nbuk) ? bs[t] : 0) + baseAll[blockIdx.x * MAXBUK + t];
    __syncthreads();
    for (int i = lo + t; i < hi; i += 256) {
        int d = dst[i], s = src[i];
        int b = d >> BSH;
        if (b < 0) b = 0; if (b >= nbuk) b = nbuk - 1;
        int slot = atomicAdd(&lcur[b], 1);
        if (slot >= 0 && slot < e)
            pairs[slot] = (((u32)d & (NPB - 1)) << 17) | ((u32)s & 0x1FFFF);
    }
}

// Phase 4: per-bucket finalize (verbatim). One block per bucket: LDS per-dst
// histogram, LDS scan, LDS-atomic ranking. Emits compact starts[].
__global__ __launch_bounds__(1024) void csr_finalize(
    const u32* __restrict__ pairs, const int* __restrict__ bs,
    int* __restrict__ starts, int* __restrict__ srcperm, int n, int e, int nbuk) {
    __shared__ int hist[NPB];
    __shared__ int excl[NPB];
    __shared__ int lcur[NPB];
    int b = blockIdx.x;
    int t = threadIdx.x;
    int d0 = b << BSH;
    int lo = bs[b], hi = bs[b + 1];
    for (int i = t; i < NPB; i += 1024) { hist[i] = 0; lcur[i] = 0; }
    __syncthreads();
    for (int i = lo + t; i < hi; i += 1024) {
        int ld = (int)(pairs[i] >> 17);          // 9 bits by construction
        atomicAdd(&hist[ld], 1);
    }
    __syncthreads();
    if (t < NPB) excl[t] = hist[t];
    __syncthreads();
    #pragma unroll
    for (int off = 1; off < NPB; off <<= 1) {
        int x = 0;
        if (t < NPB && t >= off) x = excl[t - off];
        __syncthreads();
        if (t < NPB) excl[t] += x;
        __syncthreads();
    }
    if (t < NPB) excl[t] -= hist[t];     // inclusive -> exclusive
    __syncthreads();
    if (t < NPB) {
        int d = d0 + t;
        if (d < n) starts[d] = lo + excl[t];
    }
    if (b == nbuk - 1 && t == 0) starts[n] = e;
    for (int i = lo + t; i < hi; i += 1024) {
        u32 p = pairs[i];
        int ld = (int)(p >> 17);
        int s  = (int)(p & 0x1FFFF);
        int r = atomicAdd(&lcur[ld], 1);
        int slot = lo + excl[ld] + r;
        if (slot >= 0 && slot < e) srcperm[slot] = s;
    }
}

// ---------------------------------------------------------------------------
// attn (verbatim round-4). One wave per dst node, two 32-lane halves over
// even/odd edges with independent online-softmax states (merged at end).
// ---------------------------------------------------------------------------
__global__ __launch_bounds__(256) void attn_kernel(
    const u16* __restrict__ Qb, const uint4* __restrict__ KVb,
    const int* __restrict__ starts, const int* __restrict__ srcperm,
    float* __restrict__ out, int n, int e) {
    int node = blockIdx.x * 4 + (threadIdx.x >> 6);
    int lane = threadIdx.x & 63;
    if (node >= n) return;
    int j = lane & 31;      // dim group: dims 4j..4j+3
    int h = lane >> 5;      // half: processes edges with (idx & 1) == h

    uint2 qp = *(const uint2*)(Qb + (size_t)node * HIDDEN + j * 4);
    f16x2 q01 = as_h2(qp.x), q23 = as_h2(qp.y);

    int off = starts[node];
    int deg = starts[node + 1] - off;
    if (deg < 0) deg = 0; if (deg > e) deg = e;
    if (off < 0) off = 0; if (off > e - deg) off = e - deg;

    const float LOG2E = 1.44269504f;
    float mrun = -1e30f, lrun = 0.f;
    float o0 = 0.f, o1 = 0.f, o2 = 0.f, o3 = 0.f;

    if (deg > 0) {
        const int last = deg - 1;
        const int* sp = srcperm + off;
        #define IDX(ii) (sp[((ii) > last) ? last : (ii)])
        #define KVL(s)  (KVb[(size_t)(((unsigned)(s) < (unsigned)n) ? (unsigned)(s) : 0u) * 32 + j])

        int sA = IDX(h);
        int sB = IDX(h + 2);
        int sC = IDX(h + 4);
        int sD = IDX(h + 6);
        uint4 kvA = KVL(sA);
        uint4 kvB = KVL(sB);
        (void)sA;

        for (int i = 0; i < deg; i += 2) {
            uint4 kv = kvA;
            kvA = kvB;
            kvB = KVL(sC);                  // prefetch edge i+4+h
            sC = sD;
            sD = IDX(i + 8 + h);            // prefetch index for edge i+8+h

            float p = fdot2(as_h2(kv.x), q01, fdot2(as_h2(kv.y), q23, 0.f));
            p += dpp_qperm<0xB1>(p);        // lane^1
            p += dpp_qperm<0x4E>(p);        // lane^2 -> head sum in all 4
            p *= LOG2E;                     // exp2 domain
            bool valid = (i + h) < deg;
            float pv = valid ? p : -1e30f;
            float mn  = fmaxf(mrun, pv);
            float scl = exp2f_fast(mrun - mn);
            float w   = valid ? exp2f_fast(pv - mn) : 0.f;
            lrun = lrun * scl + w;
            f16x2 vz = as_h2(kv.z), vw = as_h2(kv.w);
            o0 = o0 * scl + w * (float)vz.x;
            o1 = o1 * scl + w * (float)vz.y;
            o2 = o2 * scl + w * (float)vw.x;
            o3 = o3 * scl + w * (float)vw.y;
            mrun = mn;
        }
        #undef IDX
        #undef KVL
    }

    // merge the two half-wave states
    float mo  = __shfl_xor(mrun, 32);
    float lo_ = __shfl_xor(lrun, 32);
    float p0 = __shfl_xor(o0, 32), p1 = __shfl_xor(o1, 32);
    float p2 = __shfl_xor(o2, 32), p3 = __shfl_xor(o3, 32);
    float m2 = fmaxf(mrun, mo);
    float sa = exp2f_fast(mrun - m2), sb = exp2f_fast(mo - m2);
    float l  = lrun * sa + lo_ * sb;
    float inv = (l > 0.f) ? 1.f / l : 0.f;
    if (h == 0) {
        float4 r;
        r.x = (o0 * sa + p0 * sb) * inv;
        r.y = (o1 * sa + p1 * sb) * inv;
        r.z = (o2 * sa + p2 * sb) * inv;
        r.w = (o3 * sa + p3 * sb) * inv;
        *(float4*)(out + (size_t)node * HIDDEN + j * 4) = r;
    }
}

// ---------------------------------------------------------------------------
extern "C" void kernel_launch(void* const* d_in, const int* in_sizes, int n_in,
                              void* d_out, int out_size, void* d_ws, size_t ws_size,
                              hipStream_t stream) {
    const float* h   = (const float*)d_in[0];
    const int*   src = (const int*)d_in[1];
    const int*   dst = (const int*)d_in[2];
    const float* Wq  = (const float*)d_in[3];
    const float* bq  = (const float*)d_in[4];
    const float* Wk  = (const float*)d_in[5];
    const float* bk  = (const float*)d_in[6];
    const float* Wv  = (const float*)d_in[7];
    const float* bv  = (const float*)d_in[8];
    float* out = (float*)d_out;

    const int n = in_sizes[0] / HIDDEN;   // 100000
    const int e = in_sizes[1];            // 1600000
    const int nbuk = (n + NPB - 1) >> BSH; // 196 (<= MAXBUK)

    // Workspace carve — ~84.2 MB (ws_size >= 84.5 MB proven).
    char* ws = (char*)d_ws;
    auto align256 = [](size_t x) { return (x + 255) & ~(size_t)255; };
    int* starts  = (int*)ws; ws += align256((size_t)(n + 1) * 4);
    int* bs      = (int*)ws; ws += align256((size_t)(MAXBUK + 1) * 4);
    int* totals  = (int*)ws; ws += align256((size_t)MAXBUK * 4);
    int* histAll = (int*)ws; ws += align256((size_t)NBLK * MAXBUK * 4);
    int* baseAll = (int*)ws; ws += align256((size_t)NBLK * MAXBUK * 4);
    int* srcperm = (int*)ws; ws += align256((size_t)e * 4);
    u16* packed  = (u16*)ws; ws += align256((size_t)24 * 4 * 64 * 8 * sizeof(u16));
    u16* Qb      = (u16*)ws; ws += align256((size_t)n * HIDDEN * sizeof(u16));
    u16* KVb     = (u16*)ws; ws += align256((size_t)n * 256 * sizeof(u16));

    // pairs scratch in d_out (e*4 = 6.4MB <= 51.2MB); consumed by
    // csr_finalize before attn writes out.
    u32* pairs = (u32*)d_out;

    const int chunk = (e + NBLK - 1) / NBLK;

    pack_w_kernel<<<(24 * 4 * 64 * 8 + 255) / 256, 256, 0, stream>>>(Wq, Wk, Wv, packed);
    qkv_gemm_mfma<<<(n + 127) / 128, 256, 0, stream>>>(h, packed, bq, bk, bv, Qb, KVb, n);

    bucket_hist<<<NBLK, 256, 0, stream>>>(dst, histAll, e, nbuk, chunk);
    csr_colscan<<<MAXBUK, 256, 0, stream>>>(histAll, baseAll, totals, NBLK);
    bs_scan<<<1, 256, 0, stream>>>(totals, bs, nbuk, e);
    bucket_scatter<<<NBLK, 256, 0, stream>>>(src, dst, bs, baseAll, pairs, e, nbuk, chunk);
    csr_finalize<<<nbuk, 1024, 0, stream>>>(pairs, bs, starts, srcperm, n, e, nbuk);

    attn_kernel<<<(n + 3) / 4, 256, 0, stream>>>(Qb, (const uint4*)KVb, starts, srcperm,
                                                 out, n, e);
}